// Round 5
// baseline (212.932 us; speedup 1.0000x reference)
//
#include <hip/hip_runtime.h>

// GuidedAttentionL1Loss on MI355X — round 5.
// R1: same-address atomics serialized main (114us). R2: per-block partials +
// separate finalize -> 209us. R3 FAILED: last-block-done fusion -> per-block
// device-scope fences = L2 writeback storm on 8 XCDs (870us). R4: wave-per-
// segment + algebraic 2-round reduction -> main 42us but occupancy 25%:
// adjacent segs (1024/3072) in one block leave light waves idle while heavy
// waves finish (intra-block imbalance).
// R5: per-WAVE bundles {one 1024-seg + one 3072-seg} = uniform 16KB/wave.
// 1024 segment blocks, all 1281 blocks co-resident, no barriers in the
// segment path, uniform finish.
//
// Inputs: 0=logits[B,2] f32, 1=labels[B] i32, 2=attention_weights[T] f32,
//         3=params[P] f32, 4=xpos (recomputed analytically), 5=segment_ids
//         (unused), 6=lengths[B] i32.  Output: [loss, nll] f32.
//
// ws: starts[nseg] int at +0; partial[nseg+PARAM_BLOCKS+1] float at next
// 256B boundary ([0..nseg)=awp, [nseg..nseg+PB)=abs, [nseg+PB]=nll).

#define TPB 256
#define PARAM_BLOCKS 256

__device__ __forceinline__ void waveReduce3(float& a, float& b, float& c) {
  #pragma unroll
  for (int off = 32; off > 0; off >>= 1) {
    a += __shfl_xor(a, off, 64);
    b += __shfl_xor(b, off, 64);
    c += __shfl_xor(c, off, 64);
  }
}

__device__ __forceinline__ float blockReduceSum(float v, float* sm) {
  #pragma unroll
  for (int off = 32; off > 0; off >>= 1) v += __shfl_down(v, off, 64);
  const int lane = threadIdx.x & 63;
  const int wid  = threadIdx.x >> 6;
  if (lane == 0) sm[wid] = v;
  __syncthreads();
  float s = sm[0] + sm[1] + sm[2] + sm[3];
  __syncthreads();
  return s;
}

// ---------------------------------------------------------------- kernel A --
// Parallel exclusive scan of lengths -> starts. One block.
__global__ __launch_bounds__(TPB)
void scan_kernel(const int* __restrict__ lengths, int nseg,
                 int* __restrict__ starts) {
  __shared__ int wsum[4];
  const int t = threadIdx.x;
  const int per = (nseg + TPB - 1) / TPB;  // 32 for B=8192
  const int base = t * per;
  int local = 0;
  for (int j = 0; j < per; j++) {
    int idx = base + j;
    if (idx < nseg) local += lengths[idx];
  }
  const int lane = t & 63, wid = t >> 6;
  int incl = local;
  #pragma unroll
  for (int off = 1; off < 64; off <<= 1) {
    int n = __shfl_up(incl, off, 64);
    if (lane >= off) incl += n;
  }
  if (lane == 63) wsum[wid] = incl;
  __syncthreads();
  int wbase = 0;
  for (int i = 0; i < wid; i++) wbase += wsum[i];
  int run = wbase + incl - local;
  for (int j = 0; j < per; j++) {
    int idx = base + j;
    if (idx < nseg) { starts[idx] = run; run += lengths[idx]; }
  }
}

// ------------------------------------------------------- wave segment body --
// One 64-lane wave owns one segment. NC float4 chunks per lane:
// 4 for len=1024, 12 for len=3072. Algebraic phase-C:
// sum((w-r)^2) = sum w^2 - 2*rinv*sum(w*rh) + rinv^2*sum(rh^2).
template <int NC>
__device__ __forceinline__ float seg_wave(const float4* __restrict__ w4,
                                          int start4, int len, int lab) {
  const int lane = threadIdx.x & 63;
  const float inv_len = 1.0f / (float)len;
  float4 wv[NC];
  float aw = 0.0f, axw = 0.0f, aww = 0.0f;
  #pragma unroll
  for (int k = 0; k < NC; k++) {
    const int vi = (k << 6) + lane;  // float4 index within segment
    wv[k] = w4[start4 + vi];
    const int i0 = vi << 2;
    aw += wv[k].x + wv[k].y + wv[k].z + wv[k].w;
    axw = fmaf((float)(i0 + 1) * inv_len, wv[k].x, axw);
    axw = fmaf((float)(i0 + 2) * inv_len, wv[k].y, axw);
    axw = fmaf((float)(i0 + 3) * inv_len, wv[k].z, axw);
    axw = fmaf((float)(i0 + 4) * inv_len, wv[k].w, axw);
    aww = fmaf(wv[k].x, wv[k].x, aww);
    aww = fmaf(wv[k].y, wv[k].y, aww);
    aww = fmaf(wv[k].z, wv[k].z, aww);
    aww = fmaf(wv[k].w, wv[k].w, aww);
  }
  waveReduce3(aw, axw, aww);            // all lanes hold the sums
  const float mean = axw / aw;
  const float invstd = (float)len * (lab == 1 ? 1.0f : 0.001f);
  const float rn = 0.39894228040143267f * invstd;  // 1/(std*sqrt(2pi))
  float ar = 0.0f, awr = 0.0f, arr = 0.0f;
  #pragma unroll
  for (int k = 0; k < NC; k++) {
    const int i0 = ((k << 6) + lane) << 2;
    float z0 = ((float)(i0 + 1) * inv_len - mean) * invstd;
    float z1 = ((float)(i0 + 2) * inv_len - mean) * invstd;
    float z2 = ((float)(i0 + 3) * inv_len - mean) * invstd;
    float z3 = ((float)(i0 + 4) * inv_len - mean) * invstd;
    float r0 = __expf(-0.5f * z0 * z0) * rn;
    float r1 = __expf(-0.5f * z1 * z1) * rn;
    float r2 = __expf(-0.5f * z2 * z2) * rn;
    float r3 = __expf(-0.5f * z3 * z3) * rn;
    ar += r0 + r1 + r2 + r3;
    awr = fmaf(wv[k].x, r0, awr); awr = fmaf(wv[k].y, r1, awr);
    awr = fmaf(wv[k].z, r2, awr); awr = fmaf(wv[k].w, r3, awr);
    arr = fmaf(r0, r0, arr); arr = fmaf(r1, r1, arr);
    arr = fmaf(r2, r2, arr); arr = fmaf(r3, r3, arr);
  }
  waveReduce3(ar, awr, arr);
  const float rinv = 1.0f / (ar + 1e-6f);
  const float dsum = aww - 2.0f * rinv * awr + rinv * rinv * arr;
  return dsum * inv_len;
}

// Generic wave fallback (re-reads w; unused for this dataset's lengths).
__device__ float seg_wave_generic(const float* __restrict__ w, int start,
                                  int len, int lab) {
  const int lane = threadIdx.x & 63;
  const float inv_len = 1.0f / (float)len;
  float aw = 0.0f, axw = 0.0f, aww = 0.0f;
  for (int i = lane; i < len; i += 64) {
    float wv = w[start + i];
    aw += wv;
    axw = fmaf((float)(i + 1) * inv_len, wv, axw);
    aww = fmaf(wv, wv, aww);
  }
  waveReduce3(aw, axw, aww);
  const float mean = axw / aw;
  const float invstd = (float)len * (lab == 1 ? 1.0f : 0.001f);
  const float rn = 0.39894228040143267f * invstd;
  float ar = 0.0f, awr = 0.0f, arr = 0.0f;
  for (int i = lane; i < len; i += 64) {
    float z = ((float)(i + 1) * inv_len - mean) * invstd;
    float rh = __expf(-0.5f * z * z) * rn;
    ar += rh;
    awr = fmaf(w[start + i], rh, awr);
    arr = fmaf(rh, rh, arr);
  }
  waveReduce3(ar, awr, arr);
  const float rinv = 1.0f / (ar + 1e-6f);
  const float dsum = aww - 2.0f * rinv * awr + rinv * rinv * arr;
  return dsum * inv_len;
}

__device__ __forceinline__ void do_segment(const float* __restrict__ attw,
                                           const int* __restrict__ lengths,
                                           const int* __restrict__ starts,
                                           const int* __restrict__ labels,
                                           int seg, float* __restrict__ partial) {
  const int len = lengths[seg];
  const int start = starts[seg];
  const int lab = labels[seg];
  float r;
  if (len == 1024 && (start & 3) == 0)
    r = seg_wave<4>((const float4*)attw, start >> 2, len, lab);
  else if (len == 3072 && (start & 3) == 0)
    r = seg_wave<12>((const float4*)attw, start >> 2, len, lab);
  else
    r = seg_wave_generic(attw, start, len, lab);
  if ((threadIdx.x & 63) == 0) partial[seg] = r;
}

// ---------------------------------------------------------------- kernel B --
// Wave bundle = segments {2i, 2i+1} (one light + one heavy for this dataset)
// -> uniform 16KB per wave. 4 bundles per block, no barriers in segment path.
__global__ __launch_bounds__(TPB)
void main_kernel(const float* __restrict__ attw, const float* __restrict__ params,
                 const float* __restrict__ logits, const int* __restrict__ labels,
                 const int* __restrict__ lengths, const int* __restrict__ starts,
                 int nseg, int P, float* __restrict__ partial) {
  __shared__ float sm[4];
  const int b = blockIdx.x;
  const int nbundle = (nseg + 1) >> 1;
  const int nbunblk = (nbundle + 3) >> 2;
  if (b < nbunblk) {
    const int bun = (b << 2) + (threadIdx.x >> 6);
    if (bun < nbundle) {
      const int s0 = bun << 1;
      do_segment(attw, lengths, starts, labels, s0, partial);
      if (s0 + 1 < nseg)
        do_segment(attw, lengths, starts, labels, s0 + 1, partial);
    }
  } else if (b < nbunblk + PARAM_BLOCKS) {
    const int pb = b - nbunblk;
    const int P4 = P >> 2;
    const float4* p4 = (const float4*)params;
    float a = 0.0f;
    for (int i = pb * TPB + threadIdx.x; i < P4; i += PARAM_BLOCKS * TPB) {
      float4 v = p4[i];
      a += fabsf(v.x) + fabsf(v.y) + fabsf(v.z) + fabsf(v.w);
    }
    if (pb == 0 && threadIdx.x == 0)
      for (int i = P4 << 2; i < P; i++) a += fabsf(params[i]);
    float tot = blockReduceSum(a, sm);
    if (threadIdx.x == 0) partial[nseg + pb] = tot;
  } else {
    // NLL sum: 2-class log-softmax gather
    float acc = 0.0f;
    for (int s = threadIdx.x; s < nseg; s += TPB) {
      float l0 = logits[2 * s], l1 = logits[2 * s + 1];
      int lab = labels[s];
      float m = fmaxf(l0, l1);
      float lse = m + logf(expf(l0 - m) + expf(l1 - m));
      acc += (lab ? l1 : l0) - lse;
    }
    float tot = blockReduceSum(acc, sm);
    if (threadIdx.x == 0) partial[nseg + PARAM_BLOCKS] = tot;
  }
}

// ---------------------------------------------------------------- kernel C --
__global__ __launch_bounds__(TPB)
void finalize_kernel(const float* __restrict__ partial, int nseg,
                     float* __restrict__ out) {
  __shared__ float sm[8];
  float a_awp = 0.0f, a_abs = 0.0f;
  for (int i = threadIdx.x; i < nseg; i += TPB) a_awp += partial[i];
  for (int i = threadIdx.x; i < PARAM_BLOCKS; i += TPB) a_abs += partial[nseg + i];
  #pragma unroll
  for (int off = 32; off > 0; off >>= 1) {
    a_awp += __shfl_down(a_awp, off, 64);
    a_abs += __shfl_down(a_abs, off, 64);
  }
  const int lane = threadIdx.x & 63, wid = threadIdx.x >> 6;
  if (lane == 0) { sm[wid] = a_awp; sm[4 + wid] = a_abs; }
  __syncthreads();
  if (threadIdx.x == 0) {
    float s_awp = sm[0] + sm[1] + sm[2] + sm[3];
    float s_abs = sm[4] + sm[5] + sm[6] + sm[7];
    const float nll = -partial[nseg + PARAM_BLOCKS] / (float)nseg;
    const float penalty = 0.5f * 1e-4f * s_abs;        // ALPHA/2 * sum|p|
    const float awp = 0.5f * (s_awp / (float)nseg);    // BETA/2 * mean(per_seg)
    out[0] = nll + penalty + awp;
    out[1] = nll;
  }
}

extern "C" void kernel_launch(void* const* d_in, const int* in_sizes, int n_in,
                              void* d_out, int out_size, void* d_ws, size_t ws_size,
                              hipStream_t stream) {
  const float* logits  = (const float*)d_in[0];
  const int*   labels  = (const int*)d_in[1];
  const float* attw    = (const float*)d_in[2];
  const float* params  = (const float*)d_in[3];
  const int*   lengths = (const int*)d_in[6];
  const int nseg = in_sizes[1];
  const int P    = in_sizes[3];

  int* starts = (int*)d_ws;
  size_t poff = ((size_t)nseg * sizeof(int) + 255) & ~(size_t)255;
  float* partial = (float*)((char*)d_ws + poff);
  float* out = (float*)d_out;

  const int nbundle = (nseg + 1) >> 1;
  const int nbunblk = (nbundle + 3) >> 2;
  scan_kernel<<<1, TPB, 0, stream>>>(lengths, nseg, starts);
  main_kernel<<<nbunblk + PARAM_BLOCKS + 1, TPB, 0, stream>>>(
      attw, params, logits, labels, lengths, starts, nseg, P, partial);
  finalize_kernel<<<1, TPB, 0, stream>>>(partial, nseg, out);
}

// Round 6
// 210.499 us; speedup vs baseline: 1.0116x; 1.0116x over previous
//
#include <hip/hip_runtime.h>

// GuidedAttentionL1Loss on MI355X — round 6.
// History: R1 same-address atomics (114us main). R2 block-per-segment +
// per-block partials + separate finalize -> main <40us, total 209. R3 FAILED:
// last-block-done fusion -> per-block device fences = L2 writeback storm on
// 8 XCDs (870us). R4/R5 FAILED: wave-per-segment (long serial chains, only
// ~5-20k waves) regressed main to 42-47us at 22% occupancy — latency-bound
// kernels want MANY SHORT waves, not few long ones.
// R6: revert to R2's block-per-segment mapping (33k short waves), keep R4's
// algebra: sum((w-r)^2) = sum w^2 - 2*rinv*sum(w*rh) + rinv^2*sum(rh^2)
// -> 2 fused 3-value reduction rounds (2 barriers/block), no rv[] registers.
//
// Inputs: 0=logits[B,2] f32, 1=labels[B] i32, 2=attention_weights[T] f32,
//         3=params[P] f32, 4=xpos (recomputed analytically), 5=segment_ids
//         (unused), 6=lengths[B] i32.  Output: [loss, nll] f32.
//
// ws: starts[nseg] int at +0; partial[nseg+PARAM_BLOCKS+1] float at next
// 256B boundary ([0..nseg)=awp, [nseg..nseg+PB)=abs, [nseg+PB]=nll).

#define TPB 256
#define PARAM_BLOCKS 256

// Fused 3-value block reduction. Caller passes a 12-float LDS region; use
// DISJOINT regions for successive calls so only ONE barrier per call is
// needed (write -> sync -> read; no same-address reuse across calls).
__device__ __forceinline__ void blockReduce3(float& a, float& b, float& c,
                                             float* sm) {
  #pragma unroll
  for (int off = 32; off > 0; off >>= 1) {
    a += __shfl_xor(a, off, 64);
    b += __shfl_xor(b, off, 64);
    c += __shfl_xor(c, off, 64);
  }
  const int lane = threadIdx.x & 63, wid = threadIdx.x >> 6;
  if (lane == 0) { sm[wid] = a; sm[4 + wid] = b; sm[8 + wid] = c; }
  __syncthreads();
  a = sm[0] + sm[1] + sm[2] + sm[3];
  b = sm[4] + sm[5] + sm[6] + sm[7];
  c = sm[8] + sm[9] + sm[10] + sm[11];
}

__device__ __forceinline__ float blockReduceSum(float v, float* sm) {
  #pragma unroll
  for (int off = 32; off > 0; off >>= 1) v += __shfl_xor(v, off, 64);
  const int lane = threadIdx.x & 63, wid = threadIdx.x >> 6;
  if (lane == 0) sm[wid] = v;
  __syncthreads();
  return sm[0] + sm[1] + sm[2] + sm[3];
}

// ---------------------------------------------------------------- kernel A --
// Parallel exclusive scan of lengths -> starts. One block.
__global__ __launch_bounds__(TPB)
void scan_kernel(const int* __restrict__ lengths, int nseg,
                 int* __restrict__ starts) {
  __shared__ int wsum[4];
  const int t = threadIdx.x;
  const int per = (nseg + TPB - 1) / TPB;  // 32 for B=8192
  const int base = t * per;
  int local = 0;
  for (int j = 0; j < per; j++) {
    int idx = base + j;
    if (idx < nseg) local += lengths[idx];
  }
  const int lane = t & 63, wid = t >> 6;
  int incl = local;
  #pragma unroll
  for (int off = 1; off < 64; off <<= 1) {
    int n = __shfl_up(incl, off, 64);
    if (lane >= off) incl += n;
  }
  if (lane == 63) wsum[wid] = incl;
  __syncthreads();
  int wbase = 0;
  for (int i = 0; i < wid; i++) wbase += wsum[i];
  int run = wbase + incl - local;
  for (int j = 0; j < per; j++) {
    int idx = base + j;
    if (idx < nseg) { starts[idx] = run; run += lengths[idx]; }
  }
}

// ------------------------------------------------------------ segment body --
// Block-per-segment. NC float4 chunks per thread: 1 (len=1024), 3 (len=3072).
template <int NC>
__device__ __forceinline__ float seg_body(const float4* __restrict__ w4,
                                          int start4, int len, int lab,
                                          float* sm) {
  const float inv_len = 1.0f / (float)len;
  float4 wv[NC];
  float aw = 0.0f, axw = 0.0f, aww = 0.0f;
  #pragma unroll
  for (int k = 0; k < NC; k++) {
    const int vi = (k << 8) + threadIdx.x;  // float4 index within segment
    wv[k] = w4[start4 + vi];
    const int i0 = vi << 2;
    aw += wv[k].x + wv[k].y + wv[k].z + wv[k].w;
    axw = fmaf((float)(i0 + 1) * inv_len, wv[k].x, axw);
    axw = fmaf((float)(i0 + 2) * inv_len, wv[k].y, axw);
    axw = fmaf((float)(i0 + 3) * inv_len, wv[k].z, axw);
    axw = fmaf((float)(i0 + 4) * inv_len, wv[k].w, axw);
    aww = fmaf(wv[k].x, wv[k].x, aww);
    aww = fmaf(wv[k].y, wv[k].y, aww);
    aww = fmaf(wv[k].z, wv[k].z, aww);
    aww = fmaf(wv[k].w, wv[k].w, aww);
  }
  blockReduce3(aw, axw, aww, sm);       // region 0 (sm[0..11])
  const float mean = axw / aw;
  const float invstd = (float)len * (lab == 1 ? 1.0f : 0.001f);
  const float rn = 0.39894228040143267f * invstd;  // 1/(std*sqrt(2pi))
  const float c1 = inv_len * invstd;               // z = (i+1)*c1 - m2
  const float m2 = mean * invstd;
  float ar = 0.0f, awr = 0.0f, arr = 0.0f;
  #pragma unroll
  for (int k = 0; k < NC; k++) {
    const int i0 = (((k << 8) + threadIdx.x)) << 2;
    float z0 = fmaf((float)(i0 + 1), c1, -m2);
    float z1 = fmaf((float)(i0 + 2), c1, -m2);
    float z2 = fmaf((float)(i0 + 3), c1, -m2);
    float z3 = fmaf((float)(i0 + 4), c1, -m2);
    float r0 = __expf(-0.5f * z0 * z0) * rn;
    float r1 = __expf(-0.5f * z1 * z1) * rn;
    float r2 = __expf(-0.5f * z2 * z2) * rn;
    float r3 = __expf(-0.5f * z3 * z3) * rn;
    ar += r0 + r1 + r2 + r3;
    awr = fmaf(wv[k].x, r0, awr); awr = fmaf(wv[k].y, r1, awr);
    awr = fmaf(wv[k].z, r2, awr); awr = fmaf(wv[k].w, r3, awr);
    arr = fmaf(r0, r0, arr); arr = fmaf(r1, r1, arr);
    arr = fmaf(r2, r2, arr); arr = fmaf(r3, r3, arr);
  }
  blockReduce3(ar, awr, arr, sm + 12);  // region 1 (sm[12..23])
  const float rinv = 1.0f / (ar + 1e-6f);
  const float dsum = aww - 2.0f * rinv * awr + rinv * rinv * arr;
  return dsum * inv_len;
}

// Generic fallback (re-reads w; unused for this dataset's lengths).
__device__ float seg_generic(const float* __restrict__ w, int start, int len,
                             int lab, float* sm) {
  const float inv_len = 1.0f / (float)len;
  float aw = 0.0f, axw = 0.0f, aww = 0.0f;
  for (int i = threadIdx.x; i < len; i += TPB) {
    float wv = w[start + i];
    aw += wv;
    axw = fmaf((float)(i + 1) * inv_len, wv, axw);
    aww = fmaf(wv, wv, aww);
  }
  blockReduce3(aw, axw, aww, sm);
  const float mean = axw / aw;
  const float invstd = (float)len * (lab == 1 ? 1.0f : 0.001f);
  const float rn = 0.39894228040143267f * invstd;
  float ar = 0.0f, awr = 0.0f, arr = 0.0f;
  for (int i = threadIdx.x; i < len; i += TPB) {
    float z = ((float)(i + 1) * inv_len - mean) * invstd;
    float rh = __expf(-0.5f * z * z) * rn;
    ar += rh;
    awr = fmaf(w[start + i], rh, awr);
    arr = fmaf(rh, rh, arr);
  }
  blockReduce3(ar, awr, arr, sm + 12);
  const float rinv = 1.0f / (ar + 1e-6f);
  const float dsum = aww - 2.0f * rinv * awr + rinv * rinv * arr;
  return dsum * inv_len;
}

// ---------------------------------------------------------------- kernel B --
__global__ __launch_bounds__(TPB)
void main_kernel(const float* __restrict__ attw, const float* __restrict__ params,
                 const float* __restrict__ logits, const int* __restrict__ labels,
                 const int* __restrict__ lengths, const int* __restrict__ starts,
                 int nseg, int P, float* __restrict__ partial) {
  __shared__ float sm[24];
  const int b = blockIdx.x;
  if (b < nseg) {
    const int len = lengths[b];
    const int start = starts[b];
    const int lab = labels[b];
    float r;
    if (len == 1024 && (start & 3) == 0)
      r = seg_body<1>((const float4*)attw, start >> 2, len, lab, sm);
    else if (len == 3072 && (start & 3) == 0)
      r = seg_body<3>((const float4*)attw, start >> 2, len, lab, sm);
    else
      r = seg_generic(attw, start, len, lab, sm);
    if (threadIdx.x == 0) partial[b] = r;
  } else if (b < nseg + PARAM_BLOCKS) {
    const int pb = b - nseg;
    const int P4 = P >> 2;
    const float4* p4 = (const float4*)params;
    float a = 0.0f;
    for (int i = pb * TPB + threadIdx.x; i < P4; i += PARAM_BLOCKS * TPB) {
      float4 v = p4[i];
      a += fabsf(v.x) + fabsf(v.y) + fabsf(v.z) + fabsf(v.w);
    }
    if (pb == 0 && threadIdx.x == 0)
      for (int i = P4 << 2; i < P; i++) a += fabsf(params[i]);
    float tot = blockReduceSum(a, sm);
    if (threadIdx.x == 0) partial[nseg + pb] = tot;
  } else {
    // NLL sum: 2-class log-softmax gather
    float acc = 0.0f;
    for (int s = threadIdx.x; s < nseg; s += TPB) {
      float l0 = logits[2 * s], l1 = logits[2 * s + 1];
      int lab = labels[s];
      float m = fmaxf(l0, l1);
      float lse = m + logf(expf(l0 - m) + expf(l1 - m));
      acc += (lab ? l1 : l0) - lse;
    }
    float tot = blockReduceSum(acc, sm);
    if (threadIdx.x == 0) partial[nseg + PARAM_BLOCKS] = tot;
  }
}

// ---------------------------------------------------------------- kernel C --
__global__ __launch_bounds__(TPB)
void finalize_kernel(const float* __restrict__ partial, int nseg,
                     float* __restrict__ out) {
  __shared__ float sm[8];
  float a_awp = 0.0f, a_abs = 0.0f;
  for (int i = threadIdx.x; i < nseg; i += TPB) a_awp += partial[i];
  for (int i = threadIdx.x; i < PARAM_BLOCKS; i += TPB) a_abs += partial[nseg + i];
  #pragma unroll
  for (int off = 32; off > 0; off >>= 1) {
    a_awp += __shfl_xor(a_awp, off, 64);
    a_abs += __shfl_xor(a_abs, off, 64);
  }
  const int lane = threadIdx.x & 63, wid = threadIdx.x >> 6;
  if (lane == 0) { sm[wid] = a_awp; sm[4 + wid] = a_abs; }
  __syncthreads();
  if (threadIdx.x == 0) {
    float s_awp = sm[0] + sm[1] + sm[2] + sm[3];
    float s_abs = sm[4] + sm[5] + sm[6] + sm[7];
    const float nll = -partial[nseg + PARAM_BLOCKS] / (float)nseg;
    const float penalty = 0.5f * 1e-4f * s_abs;        // ALPHA/2 * sum|p|
    const float awp = 0.5f * (s_awp / (float)nseg);    // BETA/2 * mean(per_seg)
    out[0] = nll + penalty + awp;
    out[1] = nll;
  }
}

extern "C" void kernel_launch(void* const* d_in, const int* in_sizes, int n_in,
                              void* d_out, int out_size, void* d_ws, size_t ws_size,
                              hipStream_t stream) {
  const float* logits  = (const float*)d_in[0];
  const int*   labels  = (const int*)d_in[1];
  const float* attw    = (const float*)d_in[2];
  const float* params  = (const float*)d_in[3];
  const int*   lengths = (const int*)d_in[6];
  const int nseg = in_sizes[1];
  const int P    = in_sizes[3];

  int* starts = (int*)d_ws;
  size_t poff = ((size_t)nseg * sizeof(int) + 255) & ~(size_t)255;
  float* partial = (float*)((char*)d_ws + poff);
  float* out = (float*)d_out;

  scan_kernel<<<1, TPB, 0, stream>>>(lengths, nseg, starts);
  main_kernel<<<nseg + PARAM_BLOCKS + 1, TPB, 0, stream>>>(
      attw, params, logits, labels, lengths, starts, nseg, P, partial);
  finalize_kernel<<<1, TPB, 0, stream>>>(partial, nseg, out);
}

// Round 7
// 188.298 us; speedup vs baseline: 1.1308x; 1.1179x over previous
//
#include <hip/hip_runtime.h>

// GuidedAttentionL1Loss on MI355X — round 7.
// History: R1 same-address atomics serialize (main 114us). R2 block-per-seg +
// per-block partials + separate finalize -> main <40us, total 209. R3 FAILED:
// last-block-done fusion -> per-block device fences/atomic = serialized cache
// maintenance on 8 XCDs (870us). R4/R5 FAILED: wave-per-segment = few long
// waves, latency-bound at 22% occupancy (44us). R6: back to block-per-seg +
// algebraic 2-round reduction -> main <40us, total 210.5; profile dominated
// by harness d_ws poison (268MB, 40us) + input restores (~65us) = fixed.
// R7: (a) fold the starts-scan into each segment block (block-reduce
// lengths[0..seg), ~32 L1 loads/thread) -> 2 launches instead of 3;
// (b) dispatch NLL + param blocks FIRST so the tail is uniform short segment
// blocks; (c) __logf in NLL.
//
// Inputs: 0=logits[B,2] f32, 1=labels[B] i32, 2=attention_weights[T] f32,
//         3=params[P] f32, 4=xpos (recomputed analytically), 5=segment_ids
//         (unused), 6=lengths[B] i32.  Output: [loss, nll] f32.
//
// ws: partial[nseg+PARAM_BLOCKS+1] float at +0
//     ([0..nseg)=awp, [nseg..nseg+PB)=abs, [nseg+PB]=nll).

#define TPB 256
#define PARAM_BLOCKS 256

// Fused 3-value block reduction; caller passes a 12-float LDS region. Use
// disjoint regions for successive calls -> exactly one barrier per call.
__device__ __forceinline__ void blockReduce3(float& a, float& b, float& c,
                                             float* sm) {
  #pragma unroll
  for (int off = 32; off > 0; off >>= 1) {
    a += __shfl_xor(a, off, 64);
    b += __shfl_xor(b, off, 64);
    c += __shfl_xor(c, off, 64);
  }
  const int lane = threadIdx.x & 63, wid = threadIdx.x >> 6;
  if (lane == 0) { sm[wid] = a; sm[4 + wid] = b; sm[8 + wid] = c; }
  __syncthreads();
  a = sm[0] + sm[1] + sm[2] + sm[3];
  b = sm[4] + sm[5] + sm[6] + sm[7];
  c = sm[8] + sm[9] + sm[10] + sm[11];
}

__device__ __forceinline__ float blockReduceSum(float v, float* sm) {
  #pragma unroll
  for (int off = 32; off > 0; off >>= 1) v += __shfl_xor(v, off, 64);
  const int lane = threadIdx.x & 63, wid = threadIdx.x >> 6;
  if (lane == 0) sm[wid] = v;
  __syncthreads();
  return sm[0] + sm[1] + sm[2] + sm[3];
}

// ------------------------------------------------------------ segment body --
// Block-per-segment. NC float4 chunks per thread: 1 (len=1024), 3 (len=3072).
// Algebraic phase C: sum((w-r)^2) = sum w^2 - 2*rinv*sum(w*rh) + rinv^2*sum(rh^2).
template <int NC>
__device__ __forceinline__ float seg_body(const float4* __restrict__ w4,
                                          int start4, int len, int lab,
                                          float* sm) {
  const float inv_len = 1.0f / (float)len;
  float4 wv[NC];
  float aw = 0.0f, axw = 0.0f, aww = 0.0f;
  #pragma unroll
  for (int k = 0; k < NC; k++) {
    const int vi = (k << 8) + threadIdx.x;  // float4 index within segment
    wv[k] = w4[start4 + vi];
    const int i0 = vi << 2;
    aw += wv[k].x + wv[k].y + wv[k].z + wv[k].w;
    axw = fmaf((float)(i0 + 1) * inv_len, wv[k].x, axw);
    axw = fmaf((float)(i0 + 2) * inv_len, wv[k].y, axw);
    axw = fmaf((float)(i0 + 3) * inv_len, wv[k].z, axw);
    axw = fmaf((float)(i0 + 4) * inv_len, wv[k].w, axw);
    aww = fmaf(wv[k].x, wv[k].x, aww);
    aww = fmaf(wv[k].y, wv[k].y, aww);
    aww = fmaf(wv[k].z, wv[k].z, aww);
    aww = fmaf(wv[k].w, wv[k].w, aww);
  }
  blockReduce3(aw, axw, aww, sm);       // region 0 (sm[0..11])
  const float mean = axw / aw;
  const float invstd = (float)len * (lab == 1 ? 1.0f : 0.001f);
  const float rn = 0.39894228040143267f * invstd;  // 1/(std*sqrt(2pi))
  const float c1 = inv_len * invstd;               // z = (i+1)*c1 - m2
  const float m2 = mean * invstd;
  float ar = 0.0f, awr = 0.0f, arr = 0.0f;
  #pragma unroll
  for (int k = 0; k < NC; k++) {
    const int i0 = (((k << 8) + threadIdx.x)) << 2;
    float z0 = fmaf((float)(i0 + 1), c1, -m2);
    float z1 = fmaf((float)(i0 + 2), c1, -m2);
    float z2 = fmaf((float)(i0 + 3), c1, -m2);
    float z3 = fmaf((float)(i0 + 4), c1, -m2);
    float r0 = __expf(-0.5f * z0 * z0) * rn;
    float r1 = __expf(-0.5f * z1 * z1) * rn;
    float r2 = __expf(-0.5f * z2 * z2) * rn;
    float r3 = __expf(-0.5f * z3 * z3) * rn;
    ar += r0 + r1 + r2 + r3;
    awr = fmaf(wv[k].x, r0, awr); awr = fmaf(wv[k].y, r1, awr);
    awr = fmaf(wv[k].z, r2, awr); awr = fmaf(wv[k].w, r3, awr);
    arr = fmaf(r0, r0, arr); arr = fmaf(r1, r1, arr);
    arr = fmaf(r2, r2, arr); arr = fmaf(r3, r3, arr);
  }
  blockReduce3(ar, awr, arr, sm + 12);  // region 1 (sm[12..23])
  const float rinv = 1.0f / (ar + 1e-6f);
  const float dsum = aww - 2.0f * rinv * awr + rinv * rinv * arr;
  return dsum * inv_len;
}

// Generic fallback (re-reads w; unused for this dataset's lengths).
__device__ float seg_generic(const float* __restrict__ w, int start, int len,
                             int lab, float* sm) {
  const float inv_len = 1.0f / (float)len;
  float aw = 0.0f, axw = 0.0f, aww = 0.0f;
  for (int i = threadIdx.x; i < len; i += TPB) {
    float wv = w[start + i];
    aw += wv;
    axw = fmaf((float)(i + 1) * inv_len, wv, axw);
    aww = fmaf(wv, wv, aww);
  }
  blockReduce3(aw, axw, aww, sm);
  const float mean = axw / aw;
  const float invstd = (float)len * (lab == 1 ? 1.0f : 0.001f);
  const float rn = 0.39894228040143267f * invstd;
  float ar = 0.0f, awr = 0.0f, arr = 0.0f;
  for (int i = threadIdx.x; i < len; i += TPB) {
    float z = ((float)(i + 1) * inv_len - mean) * invstd;
    float rh = __expf(-0.5f * z * z) * rn;
    ar += rh;
    awr = fmaf(w[start + i], rh, awr);
    arr = fmaf(rh, rh, arr);
  }
  blockReduce3(ar, awr, arr, sm + 12);
  const float rinv = 1.0f / (ar + 1e-6f);
  const float dsum = aww - 2.0f * rinv * awr + rinv * rinv * arr;
  return dsum * inv_len;
}

// ---------------------------------------------------------------- kernel B --
// Block roles (dispatch order puts the serial-ish blocks first, uniform short
// segment blocks last -> clean tail):
//   b == 0                    : NLL sum
//   b in [1, 1+PARAM_BLOCKS)  : L1(params) partials
//   b >= 1+PARAM_BLOCKS       : segment seg = b - 1 - PARAM_BLOCKS
// Each segment block computes its own start = sum(lengths[0..seg)) via a
// block reduction over the (L1-resident, 32KB) lengths array — no scan kernel.
__global__ __launch_bounds__(TPB)
void main_kernel(const float* __restrict__ attw, const float* __restrict__ params,
                 const float* __restrict__ logits, const int* __restrict__ labels,
                 const int* __restrict__ lengths, int nseg, int P,
                 float* __restrict__ partial) {
  __shared__ float sm[24];
  __shared__ int smi[4];
  const int b = blockIdx.x;
  if (b == 0) {
    // NLL sum: 2-class log-softmax gather
    float acc = 0.0f;
    for (int s = threadIdx.x; s < nseg; s += TPB) {
      float l0 = logits[2 * s], l1 = logits[2 * s + 1];
      int lab = labels[s];
      float m = fmaxf(l0, l1);
      float lse = m + __logf(__expf(l0 - m) + __expf(l1 - m));
      acc += (lab ? l1 : l0) - lse;
    }
    float tot = blockReduceSum(acc, sm);
    if (threadIdx.x == 0) partial[nseg + PARAM_BLOCKS] = tot;
  } else if (b <= PARAM_BLOCKS) {
    const int pb = b - 1;
    const int P4 = P >> 2;
    const float4* p4 = (const float4*)params;
    float a = 0.0f;
    for (int i = pb * TPB + threadIdx.x; i < P4; i += PARAM_BLOCKS * TPB) {
      float4 v = p4[i];
      a += fabsf(v.x) + fabsf(v.y) + fabsf(v.z) + fabsf(v.w);
    }
    if (pb == 0 && threadIdx.x == 0)
      for (int i = P4 << 2; i < P; i++) a += fabsf(params[i]);
    float tot = blockReduceSum(a, sm);
    if (threadIdx.x == 0) partial[nseg + pb] = tot;
  } else {
    const int seg = b - 1 - PARAM_BLOCKS;
    if (seg >= nseg) return;
    // in-block exclusive prefix: start = sum(lengths[0..seg))
    int acc = 0;
    for (int i = threadIdx.x; i < seg; i += TPB) acc += lengths[i];
    #pragma unroll
    for (int off = 32; off > 0; off >>= 1) acc += __shfl_xor(acc, off, 64);
    const int lane = threadIdx.x & 63, wid = threadIdx.x >> 6;
    if (lane == 0) smi[wid] = acc;
    __syncthreads();
    const int start = smi[0] + smi[1] + smi[2] + smi[3];
    const int len = lengths[seg];
    const int lab = labels[seg];
    float r;
    if (len == 1024 && (start & 3) == 0)
      r = seg_body<1>((const float4*)attw, start >> 2, len, lab, sm);
    else if (len == 3072 && (start & 3) == 0)
      r = seg_body<3>((const float4*)attw, start >> 2, len, lab, sm);
    else
      r = seg_generic(attw, start, len, lab, sm);
    if (threadIdx.x == 0) partial[seg] = r;
  }
}

// ---------------------------------------------------------------- kernel C --
__global__ __launch_bounds__(TPB)
void finalize_kernel(const float* __restrict__ partial, int nseg,
                     float* __restrict__ out) {
  __shared__ float sm[8];
  float a_awp = 0.0f, a_abs = 0.0f;
  for (int i = threadIdx.x; i < nseg; i += TPB) a_awp += partial[i];
  for (int i = threadIdx.x; i < PARAM_BLOCKS; i += TPB) a_abs += partial[nseg + i];
  #pragma unroll
  for (int off = 32; off > 0; off >>= 1) {
    a_awp += __shfl_xor(a_awp, off, 64);
    a_abs += __shfl_xor(a_abs, off, 64);
  }
  const int lane = threadIdx.x & 63, wid = threadIdx.x >> 6;
  if (lane == 0) { sm[wid] = a_awp; sm[4 + wid] = a_abs; }
  __syncthreads();
  if (threadIdx.x == 0) {
    float s_awp = sm[0] + sm[1] + sm[2] + sm[3];
    float s_abs = sm[4] + sm[5] + sm[6] + sm[7];
    const float nll = -partial[nseg + PARAM_BLOCKS] / (float)nseg;
    const float penalty = 0.5f * 1e-4f * s_abs;        // ALPHA/2 * sum|p|
    const float awp = 0.5f * (s_awp / (float)nseg);    // BETA/2 * mean(per_seg)
    out[0] = nll + penalty + awp;
    out[1] = nll;
  }
}

extern "C" void kernel_launch(void* const* d_in, const int* in_sizes, int n_in,
                              void* d_out, int out_size, void* d_ws, size_t ws_size,
                              hipStream_t stream) {
  const float* logits  = (const float*)d_in[0];
  const int*   labels  = (const int*)d_in[1];
  const float* attw    = (const float*)d_in[2];
  const float* params  = (const float*)d_in[3];
  const int*   lengths = (const int*)d_in[6];
  const int nseg = in_sizes[1];
  const int P    = in_sizes[3];

  float* partial = (float*)d_ws;
  float* out = (float*)d_out;

  main_kernel<<<1 + PARAM_BLOCKS + nseg, TPB, 0, stream>>>(
      attw, params, logits, labels, lengths, nseg, P, partial);
  finalize_kernel<<<1, TPB, 0, stream>>>(partial, nseg, out);
}

// Round 8
// 186.642 us; speedup vs baseline: 1.1409x; 1.0089x over previous
//
#include <hip/hip_runtime.h>

// GuidedAttentionL1Loss on MI355X — round 8.
// History: R1 same-address atomics serialize (main 114us). R2 block-per-seg +
// per-block partials + separate finalize -> main <40us, total 209. R3 FAILED:
// last-block-done fusion -> per-block device fences/atomic = serialized cache
// maintenance on 8 XCDs (870us). R4/R5 FAILED: wave-per-segment = few long
// waves, latency-bound at 22% occupancy (44us). R6: block-per-seg + algebraic
// 2-round reduction -> 210.5. R7: scan folded into segment blocks (in-block
// prefix over lengths), NLL/param blocks dispatched first, 2 launches ->
// 188.3; top-5 now 100% harness reset (ws poison fills + input restores).
// R8: int4-vectorize the in-block prefix (32 -> 8 gating iterations per
// block; prefix loads sit at the head of every segment block's critical
// path). If this is <=2us, the controllable slice is at its floor.
//
// Inputs: 0=logits[B,2] f32, 1=labels[B] i32, 2=attention_weights[T] f32,
//         3=params[P] f32, 4=xpos (recomputed analytically), 5=segment_ids
//         (unused), 6=lengths[B] i32.  Output: [loss, nll] f32.
//
// ws: partial[nseg+PARAM_BLOCKS+1] float at +0
//     ([0..nseg)=awp, [nseg..nseg+PB)=abs, [nseg+PB]=nll).

#define TPB 256
#define PARAM_BLOCKS 256

// Fused 3-value block reduction; caller passes a 12-float LDS region. Use
// disjoint regions for successive calls -> exactly one barrier per call.
__device__ __forceinline__ void blockReduce3(float& a, float& b, float& c,
                                             float* sm) {
  #pragma unroll
  for (int off = 32; off > 0; off >>= 1) {
    a += __shfl_xor(a, off, 64);
    b += __shfl_xor(b, off, 64);
    c += __shfl_xor(c, off, 64);
  }
  const int lane = threadIdx.x & 63, wid = threadIdx.x >> 6;
  if (lane == 0) { sm[wid] = a; sm[4 + wid] = b; sm[8 + wid] = c; }
  __syncthreads();
  a = sm[0] + sm[1] + sm[2] + sm[3];
  b = sm[4] + sm[5] + sm[6] + sm[7];
  c = sm[8] + sm[9] + sm[10] + sm[11];
}

__device__ __forceinline__ float blockReduceSum(float v, float* sm) {
  #pragma unroll
  for (int off = 32; off > 0; off >>= 1) v += __shfl_xor(v, off, 64);
  const int lane = threadIdx.x & 63, wid = threadIdx.x >> 6;
  if (lane == 0) sm[wid] = v;
  __syncthreads();
  return sm[0] + sm[1] + sm[2] + sm[3];
}

// ------------------------------------------------------------ segment body --
// Block-per-segment. NC float4 chunks per thread: 1 (len=1024), 3 (len=3072).
// Algebraic phase C: sum((w-r)^2) = sum w^2 - 2*rinv*sum(w*rh) + rinv^2*sum(rh^2).
template <int NC>
__device__ __forceinline__ float seg_body(const float4* __restrict__ w4,
                                          int start4, int len, int lab,
                                          float* sm) {
  const float inv_len = 1.0f / (float)len;
  float4 wv[NC];
  float aw = 0.0f, axw = 0.0f, aww = 0.0f;
  #pragma unroll
  for (int k = 0; k < NC; k++) {
    const int vi = (k << 8) + threadIdx.x;  // float4 index within segment
    wv[k] = w4[start4 + vi];
    const int i0 = vi << 2;
    aw += wv[k].x + wv[k].y + wv[k].z + wv[k].w;
    axw = fmaf((float)(i0 + 1) * inv_len, wv[k].x, axw);
    axw = fmaf((float)(i0 + 2) * inv_len, wv[k].y, axw);
    axw = fmaf((float)(i0 + 3) * inv_len, wv[k].z, axw);
    axw = fmaf((float)(i0 + 4) * inv_len, wv[k].w, axw);
    aww = fmaf(wv[k].x, wv[k].x, aww);
    aww = fmaf(wv[k].y, wv[k].y, aww);
    aww = fmaf(wv[k].z, wv[k].z, aww);
    aww = fmaf(wv[k].w, wv[k].w, aww);
  }
  blockReduce3(aw, axw, aww, sm);       // region 0 (sm[0..11])
  const float mean = axw / aw;
  const float invstd = (float)len * (lab == 1 ? 1.0f : 0.001f);
  const float rn = 0.39894228040143267f * invstd;  // 1/(std*sqrt(2pi))
  const float c1 = inv_len * invstd;               // z = (i+1)*c1 - m2
  const float m2 = mean * invstd;
  float ar = 0.0f, awr = 0.0f, arr = 0.0f;
  #pragma unroll
  for (int k = 0; k < NC; k++) {
    const int i0 = (((k << 8) + threadIdx.x)) << 2;
    float z0 = fmaf((float)(i0 + 1), c1, -m2);
    float z1 = fmaf((float)(i0 + 2), c1, -m2);
    float z2 = fmaf((float)(i0 + 3), c1, -m2);
    float z3 = fmaf((float)(i0 + 4), c1, -m2);
    float r0 = __expf(-0.5f * z0 * z0) * rn;
    float r1 = __expf(-0.5f * z1 * z1) * rn;
    float r2 = __expf(-0.5f * z2 * z2) * rn;
    float r3 = __expf(-0.5f * z3 * z3) * rn;
    ar += r0 + r1 + r2 + r3;
    awr = fmaf(wv[k].x, r0, awr); awr = fmaf(wv[k].y, r1, awr);
    awr = fmaf(wv[k].z, r2, awr); awr = fmaf(wv[k].w, r3, awr);
    arr = fmaf(r0, r0, arr); arr = fmaf(r1, r1, arr);
    arr = fmaf(r2, r2, arr); arr = fmaf(r3, r3, arr);
  }
  blockReduce3(ar, awr, arr, sm + 12);  // region 1 (sm[12..23])
  const float rinv = 1.0f / (ar + 1e-6f);
  const float dsum = aww - 2.0f * rinv * awr + rinv * rinv * arr;
  return dsum * inv_len;
}

// Generic fallback (re-reads w; unused for this dataset's lengths).
__device__ float seg_generic(const float* __restrict__ w, int start, int len,
                             int lab, float* sm) {
  const float inv_len = 1.0f / (float)len;
  float aw = 0.0f, axw = 0.0f, aww = 0.0f;
  for (int i = threadIdx.x; i < len; i += TPB) {
    float wv = w[start + i];
    aw += wv;
    axw = fmaf((float)(i + 1) * inv_len, wv, axw);
    aww = fmaf(wv, wv, aww);
  }
  blockReduce3(aw, axw, aww, sm);
  const float mean = axw / aw;
  const float invstd = (float)len * (lab == 1 ? 1.0f : 0.001f);
  const float rn = 0.39894228040143267f * invstd;
  float ar = 0.0f, awr = 0.0f, arr = 0.0f;
  for (int i = threadIdx.x; i < len; i += TPB) {
    float z = ((float)(i + 1) * inv_len - mean) * invstd;
    float rh = __expf(-0.5f * z * z) * rn;
    ar += rh;
    awr = fmaf(w[start + i], rh, awr);
    arr = fmaf(rh, rh, arr);
  }
  blockReduce3(ar, awr, arr, sm + 12);
  const float rinv = 1.0f / (ar + 1e-6f);
  const float dsum = aww - 2.0f * rinv * awr + rinv * rinv * arr;
  return dsum * inv_len;
}

// ---------------------------------------------------------------- kernel B --
// Block roles (serial-ish blocks dispatch first; uniform short segment blocks
// form the tail):
//   b == 0                    : NLL sum
//   b in [1, 1+PARAM_BLOCKS)  : L1(params) partials
//   b >= 1+PARAM_BLOCKS       : segment seg = b - 1 - PARAM_BLOCKS
// Each segment block computes start = sum(lengths[0..seg)) via an
// int4-vectorized block reduction (L1-resident array; 8 gating iterations).
__global__ __launch_bounds__(TPB)
void main_kernel(const float* __restrict__ attw, const float* __restrict__ params,
                 const float* __restrict__ logits, const int* __restrict__ labels,
                 const int* __restrict__ lengths, int nseg, int P,
                 float* __restrict__ partial) {
  __shared__ float sm[24];
  __shared__ int smi[4];
  const int b = blockIdx.x;
  if (b == 0) {
    // NLL sum: 2-class log-softmax gather
    float acc = 0.0f;
    for (int s = threadIdx.x; s < nseg; s += TPB) {
      float l0 = logits[2 * s], l1 = logits[2 * s + 1];
      int lab = labels[s];
      float m = fmaxf(l0, l1);
      float lse = m + __logf(__expf(l0 - m) + __expf(l1 - m));
      acc += (lab ? l1 : l0) - lse;
    }
    float tot = blockReduceSum(acc, sm);
    if (threadIdx.x == 0) partial[nseg + PARAM_BLOCKS] = tot;
  } else if (b <= PARAM_BLOCKS) {
    const int pb = b - 1;
    const int P4 = P >> 2;
    const float4* p4 = (const float4*)params;
    float a = 0.0f;
    for (int i = pb * TPB + threadIdx.x; i < P4; i += PARAM_BLOCKS * TPB) {
      float4 v = p4[i];
      a += fabsf(v.x) + fabsf(v.y) + fabsf(v.z) + fabsf(v.w);
    }
    if (pb == 0 && threadIdx.x == 0)
      for (int i = P4 << 2; i < P; i++) a += fabsf(params[i]);
    float tot = blockReduceSum(a, sm);
    if (threadIdx.x == 0) partial[nseg + pb] = tot;
  } else {
    const int seg = b - 1 - PARAM_BLOCKS;
    if (seg >= nseg) return;
    // int4-vectorized exclusive prefix: start = sum(lengths[0..seg))
    int acc = 0;
    const int n4 = seg >> 2;
    const int4* l4 = (const int4*)lengths;
    for (int i = threadIdx.x; i < n4; i += TPB) {
      int4 v = l4[i];
      acc += v.x + v.y + v.z + v.w;
    }
    if (threadIdx.x < (seg & 3)) acc += lengths[(n4 << 2) + threadIdx.x];
    #pragma unroll
    for (int off = 32; off > 0; off >>= 1) acc += __shfl_xor(acc, off, 64);
    const int lane = threadIdx.x & 63, wid = threadIdx.x >> 6;
    if (lane == 0) smi[wid] = acc;
    __syncthreads();
    const int start = smi[0] + smi[1] + smi[2] + smi[3];
    const int len = lengths[seg];
    const int lab = labels[seg];
    float r;
    if (len == 1024 && (start & 3) == 0)
      r = seg_body<1>((const float4*)attw, start >> 2, len, lab, sm);
    else if (len == 3072 && (start & 3) == 0)
      r = seg_body<3>((const float4*)attw, start >> 2, len, lab, sm);
    else
      r = seg_generic(attw, start, len, lab, sm);
    if (threadIdx.x == 0) partial[seg] = r;
  }
}

// ---------------------------------------------------------------- kernel C --
__global__ __launch_bounds__(TPB)
void finalize_kernel(const float* __restrict__ partial, int nseg,
                     float* __restrict__ out) {
  __shared__ float sm[8];
  float a_awp = 0.0f, a_abs = 0.0f;
  for (int i = threadIdx.x; i < nseg; i += TPB) a_awp += partial[i];
  for (int i = threadIdx.x; i < PARAM_BLOCKS; i += TPB) a_abs += partial[nseg + i];
  #pragma unroll
  for (int off = 32; off > 0; off >>= 1) {
    a_awp += __shfl_xor(a_awp, off, 64);
    a_abs += __shfl_xor(a_abs, off, 64);
  }
  const int lane = threadIdx.x & 63, wid = threadIdx.x >> 6;
  if (lane == 0) { sm[wid] = a_awp; sm[4 + wid] = a_abs; }
  __syncthreads();
  if (threadIdx.x == 0) {
    float s_awp = sm[0] + sm[1] + sm[2] + sm[3];
    float s_abs = sm[4] + sm[5] + sm[6] + sm[7];
    const float nll = -partial[nseg + PARAM_BLOCKS] / (float)nseg;
    const float penalty = 0.5f * 1e-4f * s_abs;        // ALPHA/2 * sum|p|
    const float awp = 0.5f * (s_awp / (float)nseg);    // BETA/2 * mean(per_seg)
    out[0] = nll + penalty + awp;
    out[1] = nll;
  }
}

extern "C" void kernel_launch(void* const* d_in, const int* in_sizes, int n_in,
                              void* d_out, int out_size, void* d_ws, size_t ws_size,
                              hipStream_t stream) {
  const float* logits  = (const float*)d_in[0];
  const int*   labels  = (const int*)d_in[1];
  const float* attw    = (const float*)d_in[2];
  const float* params  = (const float*)d_in[3];
  const int*   lengths = (const int*)d_in[6];
  const int nseg = in_sizes[1];
  const int P    = in_sizes[3];

  float* partial = (float*)d_ws;
  float* out = (float*)d_out;

  main_kernel<<<1 + PARAM_BLOCKS + nseg, TPB, 0, stream>>>(
      attw, params, logits, labels, lengths, nseg, P, partial);
  finalize_kernel<<<1, TPB, 0, stream>>>(partial, nseg, out);
}